// Round 10
// baseline (331.616 us; speedup 1.0000x reference)
//
#include <hip/hip_runtime.h>

#define NN 20000
#define NE 320000
#define FIN 64
#define HD 256
#define NC 10
#define NG 64
#define NB ((NN + 255) / 256)     // 79 scan blocks
#define EBMAX (NE + 3 * NN + 4)   // padded CSR upper bound (u16 slots), pad-4

typedef unsigned short u16;
typedef unsigned int u32;
typedef __attribute__((ext_vector_type(8))) short short8;   // 8 bf16 (4 VGPRs)
typedef __attribute__((ext_vector_type(4))) float f32x4;    // 4 fp32 acc

__device__ __forceinline__ float bf2f(u16 u) {
    union { u32 i; float f; } v; v.i = ((u32)u) << 16; return v.f;
}
__device__ __forceinline__ u16 f2bf(float f) {
    union { float f; u32 i; } v; v.f = f;
    u32 r = v.i + 0x7fffu + ((v.i >> 16) & 1u);   // RNE
    return (u16)(r >> 16);
}
__device__ __forceinline__ void accum4(float* acc, const uint2& v) {
    acc[0] += bf2f((u16)(v.x & 0xffff)); acc[1] += bf2f((u16)(v.x >> 16));
    acc[2] += bf2f((u16)(v.y & 0xffff)); acc[3] += bf2f((u16)(v.y >> 16));
}

// ------- degree count + graph bounds + ebuf pad-fill (merged, 1 launch) ----
__global__ void k_degpad(const int* __restrict__ col, int* __restrict__ degi,
                         const int* __restrict__ batch, int* __restrict__ gstart,
                         u32* __restrict__ ebuf32) {
    int i = blockIdx.x * 256 + threadIdx.x;
    if (i < NE) atomicAdd(&degi[col[i]], 1);
    if (i < NN) {
        int b = batch[i];
        int prev = (i == 0) ? -1 : batch[i - 1];
        if (b != prev) gstart[b] = i;
    }
    if (i < EBMAX / 2) ebuf32[i] = 0x4E204E20u;   // two u16 = NN, NN (zero row)
}

// ---------------- scan stage 1: padded-degree block scan + block sums ------
__global__ __launch_bounds__(256) void k_scan1(const int* __restrict__ degi,
                                               int* __restrict__ rowptr,
                                               int* __restrict__ bsum) {
    int t = threadIdx.x;
    int i = blockIdx.x * 256 + t;
    int v = (i < NN) ? ((degi[i] + 3) & ~3) : 0;   // padded degree (4)
    int lane = t & 63, wid = t >> 6;
    int x = v;
#pragma unroll
    for (int off = 1; off < 64; off <<= 1) {
        int y = __shfl_up(x, off);
        if (lane >= off) x += y;
    }
    __shared__ int ws[4];
    if (lane == 63) ws[wid] = x;
    __syncthreads();
    int woff = 0;
    for (int w = 0; w < wid; ++w) woff += ws[w];
    if (i < NN) rowptr[i] = woff + x - v;
    if (t == 255) bsum[blockIdx.x] = woff + x;
}

// ---------------- scan 2+3 fused: fixup + cursor + dinv + u0 (+zero row NN)
__global__ void k_scan3(const int* __restrict__ degi, const int* __restrict__ bsum,
                        int* __restrict__ rowptr, int* __restrict__ cursor,
                        float* __restrict__ dinv,
                        const float* __restrict__ x, u16* __restrict__ u0) {
    __shared__ int pref[NB];
    if (threadIdx.x < NB) pref[threadIdx.x] = bsum[threadIdx.x];
    __syncthreads();
    if (threadIdx.x == 0) {
        int run = 0;
        for (int k = 0; k < NB; ++k) { int t = pref[k]; pref[k] = run; run += t; }
    }
    __syncthreads();
    int i = blockIdx.x * 256 + threadIdx.x;
    if (i < NN) {
        int dg = degi[i];
        int rp = rowptr[i] + pref[i >> 8];
        rowptr[i] = rp;
        cursor[i] = rp;
        dinv[i] = rsqrtf((float)(1 + dg));
        if (i == NN - 1) rowptr[NN] = rp + ((dg + 3) & ~3);
    }
    if (i < NN * FIN / 4) {
        int node = i >> 4;
        float d = rsqrtf((float)(1 + degi[node]));
        float4 v = *(const float4*)&x[(size_t)i * 4];
        u32 lo = (u32)f2bf(v.x * d) | ((u32)f2bf(v.y * d) << 16);
        u32 hi = (u32)f2bf(v.z * d) | ((u32)f2bf(v.w * d) << 16);
        *(uint2*)&u0[(size_t)i * 4] = make_uint2(lo, hi);
    }
    if (blockIdx.x == 0 && threadIdx.x < FIN) u0[(size_t)NN * FIN + threadIdx.x] = 0;  // dummy row
}

// ---------------- fill CSR buckets (u16 payload) ----------------
__global__ void k_fill(const int* __restrict__ row, const int* __restrict__ col,
                       int* __restrict__ cursor, u16* __restrict__ ebuf) {
    int e = blockIdx.x * 256 + threadIdx.x;
    if (e < NE) {
        int c = col[e];
        int pos = atomicAdd(&cursor[c], 1);
        ebuf[pos] = (u16)row[e];
    }
}

// ---------------- LDS-tiled transpose+cast of all 5 W ----------------
__global__ __launch_bounds__(256) void k_trans(const float* __restrict__ W0, const float* __restrict__ W1,
                                               const float* __restrict__ W2, const float* __restrict__ W3,
                                               const float* __restrict__ W4,
                                               u16* __restrict__ T0, u16* __restrict__ T1,
                                               u16* __restrict__ T2, u16* __restrict__ T3,
                                               u16* __restrict__ T4) {
    int l = blockIdx.z;
    const float* W = (l == 0) ? W0 : (l == 1) ? W1 : (l == 2) ? W2 : (l == 3) ? W3 : W4;
    u16* T = (l == 0) ? T0 : (l == 1) ? T1 : (l == 2) ? T2 : (l == 3) ? T3 : T4;
    int K = (l == 0) ? FIN : HD;
    int k0 = blockIdx.x * 32;
    if (k0 >= K) return;
    int n0 = blockIdx.y * 32;
    __shared__ float tile[32][33];
    int tx = threadIdx.x & 31, ty = threadIdx.x >> 5;
#pragma unroll
    for (int r = 0; r < 32; r += 8)
        tile[ty + r][tx] = W[(size_t)(k0 + ty + r) * HD + n0 + tx];
    __syncthreads();
#pragma unroll
    for (int r = 0; r < 32; r += 8)
        T[(size_t)(n0 + ty + r) * K + k0 + tx] = f2bf(tile[tx][ty + r]);
}

// ============ FUSED gather(aggregate) + MFMA matmul, 16-row tile/block =====
// r9 structure with pad-4 CSR (−10% gather slots, the one axis time responds
// to). 256-wide: full-row no-reduce, chunk = 4 slots (one uint2 id broadcast,
// 4 row loads, lane-local accumulate). 64-wide: 4 groups x 16 lanes, lane
// owns 4 feats, 2-stage shfl reduce.
__global__ __launch_bounds__(512, 8) void k_fused(const u16* __restrict__ U,
                                                  const int* __restrict__ rowptr,
                                                  const u16* __restrict__ ebuf,
                                                  const float* __restrict__ dinv,
                                                  const u16* __restrict__ Wt,
                                                  const float* __restrict__ bias,
                                                  u16* __restrict__ O,
                                                  int K, int scaleOut) {
    __shared__ u16 Asm[16][264];     // 16 rows x (K<=256 + 8 pad) bf16
    __shared__ u16 Bsm[256][40];
    __shared__ float bs[HD];
    const int m0 = blockIdx.x * 16;  // 1250 * 16 == 20000, exact
    const int t = threadIdx.x;
    const int wave = t >> 6;         // 0..7
    const int lane = t & 63;
    if (t < HD) bs[t] = bias[t];
    if (blockIdx.x == 0 && t < HD) O[(size_t)NN * HD + t] = 0;   // dummy row

    // ---------------- gather phase ----------------
    if (K == HD) {
        // full-row: task = node, 16 tasks, 2/wave; lane owns feats [lane*4, lane*4+4)
        const int f0 = lane * 4;
        for (int task = wave; task < 16; task += 8) {
            const int n = m0 + task;
            const int s = rowptr[n], e = rowptr[n + 1];
            float acc[4];
            {   // self-loop (every lane owns its 4 feats)
                uint2 sv = *(const uint2*)&U[(size_t)n * HD + f0];
                acc[0] = bf2f((u16)(sv.x & 0xffff)); acc[1] = bf2f((u16)(sv.x >> 16));
                acc[2] = bf2f((u16)(sv.y & 0xffff)); acc[3] = bf2f((u16)(sv.y >> 16));
            }
            for (int j0 = s; j0 < e; j0 += 4) {
                uint2 iv = *(const uint2*)&ebuf[j0];   // 4 ids, broadcast (1 line)
                uint2 v0 = *(const uint2*)&U[(size_t)(iv.x & 0xffff) * HD + f0];
                uint2 v1 = *(const uint2*)&U[(size_t)(iv.x >> 16)    * HD + f0];
                uint2 v2 = *(const uint2*)&U[(size_t)(iv.y & 0xffff) * HD + f0];
                uint2 v3 = *(const uint2*)&U[(size_t)(iv.y >> 16)    * HD + f0];
                accum4(acc, v0); accum4(acc, v1); accum4(acc, v2); accum4(acc, v3);
            }
            float d = dinv[n];
            uint2 o;
            o.x = (u32)f2bf(acc[0] * d) | ((u32)f2bf(acc[1] * d) << 16);
            o.y = (u32)f2bf(acc[2] * d) | ((u32)f2bf(acc[3] * d) << 16);
            *(uint2*)&Asm[task][f0] = o;
        }
    } else {
        // 64-wide rows (layer 1): 4 groups x 16 lanes; lane owns 4 feats.
        const int grp = lane >> 4;       // 0..3 (slot within 4-chunk)
        const int seg = lane & 15;       // feats [seg*4, seg*4+4)
        for (int task = wave; task < 16; task += 8) {
            const int n = m0 + task;
            const int s = rowptr[n], e = rowptr[n + 1];
            float acc[4];
            if (grp == 0) {
                uint2 v = *(const uint2*)&U[(size_t)n * FIN + seg * 4];
                acc[0] = bf2f((u16)(v.x & 0xffff)); acc[1] = bf2f((u16)(v.x >> 16));
                acc[2] = bf2f((u16)(v.y & 0xffff)); acc[3] = bf2f((u16)(v.y >> 16));
            } else {
#pragma unroll
                for (int k = 0; k < 4; ++k) acc[k] = 0.f;
            }
            for (int j = s; j < e; j += 4) {
                int r0 = (int)ebuf[j + grp];                      // pads -> row NN
                uint2 v0 = *(const uint2*)&U[(size_t)r0 * FIN + seg * 4];
                accum4(acc, v0);
            }
#pragma unroll
            for (int k = 0; k < 4; ++k) {
                acc[k] += __shfl_xor(acc[k], 16);
                acc[k] += __shfl_xor(acc[k], 32);
            }
            if (grp == 0) {
                float d = dinv[n];
                uint2 o;
                o.x = (u32)f2bf(acc[0] * d) | ((u32)f2bf(acc[1] * d) << 16);
                o.y = (u32)f2bf(acc[2] * d) | ((u32)f2bf(acc[3] * d) << 16);
                *(uint2*)&Asm[task][seg * 4] = o;
            }
        }
    }
    __syncthreads();

    // ---------------- MFMA phase (Bsm cooperative staging) ----------------
    const int quad = lane >> 4;
    const int l16 = lane & 15;
    const int n0 = wave * 32;        // wave owns N columns [n0, n0+32)
    f32x4 acc[2];
#pragma unroll
    for (int j = 0; j < 2; ++j) acc[j] = (f32x4){0.f, 0.f, 0.f, 0.f};

    for (int k0 = 0; k0 < K; k0 += 32) {
        {   // stage Wt[:, k0:k0+32] (16 KB) with all 512 threads
            int r = t >> 1, h16 = (t & 1) * 16;
#pragma unroll
            for (int j = 0; j < 2; ++j) {
                float4 v = *(const float4*)&Wt[(size_t)r * K + k0 + h16 + j * 8];
                *(float4*)&Bsm[r][h16 + j * 8] = v;
            }
        }
        __syncthreads();
        short8 a = *(const short8*)&Asm[l16][k0 + quad * 8];
        short8 b[2];
#pragma unroll
        for (int j = 0; j < 2; ++j) b[j] = *(const short8*)&Bsm[n0 + j * 16 + l16][quad * 8];
#pragma unroll
        for (int j = 0; j < 2; ++j)
            acc[j] = __builtin_amdgcn_mfma_f32_16x16x32_bf16(a, b[j], acc[j], 0, 0, 0);
        __syncthreads();
    }
#pragma unroll
    for (int r = 0; r < 4; ++r) {
        int m = m0 + quad * 4 + r;
        float d = scaleOut ? dinv[m] : 1.0f;
#pragma unroll
        for (int j = 0; j < 2; ++j) {
            int n = n0 + j * 16 + l16;
            float val = fmaxf(acc[j][r] + bs[n], 0.f) * d;
            O[(size_t)m * HD + n] = f2bf(val);
        }
    }
}

// ---------------- fused pool + head (512 thr: 2 node-stripes) ----------------
__global__ __launch_bounds__(512) void k_poolout(const u16* __restrict__ h,
                                                 const int* __restrict__ gstart,
                                                 const float* __restrict__ Wout,
                                                 const float* __restrict__ bout,
                                                 float* __restrict__ out) {
    int g = blockIdx.x;
    int t = threadIdx.x;
    int f = t & (HD - 1);
    int half = t >> 8;               // 0 or 1
    __shared__ float pp[2][HD];
    __shared__ float pooled[HD];
    __shared__ float part[NC][16];
    __shared__ int s_se[2];
    if (t == 0) {
        int st = gstart[g];
        int en = NN;
        for (int gg = g + 1; gg < NG; ++gg) en = min(en, gstart[gg]);
        s_se[0] = st; s_se[1] = en;
    }
    __syncthreads();
    int st = s_se[0], en = s_se[1];
    float a0 = 0.f, a1 = 0.f, a2 = 0.f, a3 = 0.f;
    int n = st + half;
    for (; n + 6 < en; n += 8) {
        a0 += bf2f(h[(size_t)n * HD + f]);
        a1 += bf2f(h[(size_t)(n + 2) * HD + f]);
        a2 += bf2f(h[(size_t)(n + 4) * HD + f]);
        a3 += bf2f(h[(size_t)(n + 6) * HD + f]);
    }
    for (; n < en; n += 2) a0 += bf2f(h[(size_t)n * HD + f]);
    pp[half][f] = a0 + a1 + a2 + a3;
    __syncthreads();
    if (t < HD) {
        float inv = 1.0f / (float)max(en - st, 1);
        pooled[t] = (pp[0][t] + pp[1][t]) * inv;
    }
    __syncthreads();
    if (t < NC * 16) {
        int c = t >> 4, l16 = t & 15;
        float s = 0.f;
        for (int ff = l16; ff < HD; ff += 16)
            s = fmaf(pooled[ff], Wout[(size_t)ff * NC + c], s);
        part[c][l16] = s;
    }
    __syncthreads();
    if (t < NC) {
        float s = 0.f;
#pragma unroll
        for (int k = 0; k < 16; ++k) s += part[t][k];
        out[(size_t)g * NC + t] = s + bout[t];
    }
}

extern "C" void kernel_launch(void* const* d_in, const int* in_sizes, int n_in,
                              void* d_out, int out_size, void* d_ws, size_t ws_size,
                              hipStream_t stream) {
    const float* x     = (const float*)d_in[0];
    const int*   ei    = (const int*)d_in[1];
    const int*   batch = (const int*)d_in[2];
    const float* Wl[5] = {(const float*)d_in[3], (const float*)d_in[5], (const float*)d_in[7],
                          (const float*)d_in[9], (const float*)d_in[11]};
    const float* bl[5] = {(const float*)d_in[4], (const float*)d_in[6], (const float*)d_in[8],
                          (const float*)d_in[10], (const float*)d_in[12]};
    const float* Wout = (const float*)d_in[13];
    const float* bout = (const float*)d_in[14];
    float* out = (float*)d_out;

    const int* row = ei;
    const int* col = ei + NE;

    char* p = (char*)d_ws;
    auto take = [&](size_t bytes) { char* q = p; p += (bytes + 255) & ~(size_t)255; return q; };
    float* dinv   = (float*)take(NN * 4);
    int*   degi   = (int*)take(NN * 4);
    int*   rowptr = (int*)take((NN + 1) * 4);
    int*   cursor = (int*)take(NN * 4);
    int*   bsum   = (int*)take(NB * 4);
    u16*   ebuf   = (u16*)take(EBMAX * 2);
    int*   gstart = (int*)take(NG * 4);
    u16*   Wt[5];
    for (int l = 0; l < 5; ++l) Wt[l] = (u16*)take((size_t)HD * HD * 2);
    u16*   B1     = (u16*)take((size_t)(NN + 1) * HD * 2);   // +1 dummy zero row
    u16*   B2     = (u16*)take((size_t)(NN + 1) * HD * 2);

    hipMemsetAsync(degi, 0, NN * 4, stream);
    hipMemsetAsync(gstart, 0x7F, NG * 4, stream);   // sentinel > NN
    k_degpad<<<(NE + 255) / 256, 256, 0, stream>>>(col, degi, batch, gstart, (u32*)ebuf);
    k_scan1<<<NB, 256, 0, stream>>>(degi, rowptr, bsum);
    k_scan3<<<(NN * FIN / 4 + 255) / 256, 256, 0, stream>>>(degi, bsum, rowptr, cursor, dinv, x, B1);
    k_fill<<<(NE + 255) / 256, 256, 0, stream>>>(row, col, cursor, ebuf);
    dim3 tGrid(8, 8, 5);
    k_trans<<<tGrid, 256, 0, stream>>>(Wl[0], Wl[1], Wl[2], Wl[3], Wl[4],
                                       Wt[0], Wt[1], Wt[2], Wt[3], Wt[4]);

    // 5 fused layers, ping-pong B1 <-> B2 (U != O, no read/write hazard)
    const int fGrid = NN / 16;   // 1250, exact
    k_fused<<<fGrid, 512, 0, stream>>>(B1, rowptr, ebuf, dinv, Wt[0], bl[0], B2, FIN, 1);
    k_fused<<<fGrid, 512, 0, stream>>>(B2, rowptr, ebuf, dinv, Wt[1], bl[1], B1, HD, 1);
    k_fused<<<fGrid, 512, 0, stream>>>(B1, rowptr, ebuf, dinv, Wt[2], bl[2], B2, HD, 1);
    k_fused<<<fGrid, 512, 0, stream>>>(B2, rowptr, ebuf, dinv, Wt[3], bl[3], B1, HD, 1);
    k_fused<<<fGrid, 512, 0, stream>>>(B1, rowptr, ebuf, dinv, Wt[4], bl[4], B2, HD, 0);

    k_poolout<<<NG, 512, 0, stream>>>(B2, gstart, Wout, bout, out);
}

// Round 11
// 321.404 us; speedup vs baseline: 1.0318x; 1.0318x over previous
//
#include <hip/hip_runtime.h>

#define NN 20000
#define NE 320000
#define FIN 64
#define HD 256
#define NC 10
#define NG 64
#define NB ((NN + 255) / 256)     // 79 scan blocks
#define EBMAX (NE + 7 * NN + 8)   // padded CSR upper bound (u16 slots), pad-8

typedef unsigned short u16;
typedef unsigned int u32;
typedef __attribute__((ext_vector_type(8))) short short8;   // 8 bf16 (4 VGPRs)
typedef __attribute__((ext_vector_type(4))) float f32x4;    // 4 fp32 acc

__device__ __forceinline__ float bf2f(u16 u) {
    union { u32 i; float f; } v; v.i = ((u32)u) << 16; return v.f;
}
__device__ __forceinline__ u16 f2bf(float f) {
    union { float f; u32 i; } v; v.f = f;
    u32 r = v.i + 0x7fffu + ((v.i >> 16) & 1u);   // RNE
    return (u16)(r >> 16);
}
__device__ __forceinline__ void accum8(float* acc, const uint4& v) {
    acc[0] += bf2f((u16)(v.x & 0xffff)); acc[1] += bf2f((u16)(v.x >> 16));
    acc[2] += bf2f((u16)(v.y & 0xffff)); acc[3] += bf2f((u16)(v.y >> 16));
    acc[4] += bf2f((u16)(v.z & 0xffff)); acc[5] += bf2f((u16)(v.z >> 16));
    acc[6] += bf2f((u16)(v.w & 0xffff)); acc[7] += bf2f((u16)(v.w >> 16));
}
__device__ __forceinline__ void accum4(float* acc, const uint2& v) {
    acc[0] += bf2f((u16)(v.x & 0xffff)); acc[1] += bf2f((u16)(v.x >> 16));
    acc[2] += bf2f((u16)(v.y & 0xffff)); acc[3] += bf2f((u16)(v.y >> 16));
}

// ------- degree count + graph bounds + ebuf pad-fill (merged, 1 launch) ----
__global__ void k_degpad(const int* __restrict__ col, int* __restrict__ degi,
                         const int* __restrict__ batch, int* __restrict__ gstart,
                         u32* __restrict__ ebuf32) {
    int i = blockIdx.x * 256 + threadIdx.x;
    if (i < NE) atomicAdd(&degi[col[i]], 1);
    if (i < NN) {
        int b = batch[i];
        int prev = (i == 0) ? -1 : batch[i - 1];
        if (b != prev) gstart[b] = i;
    }
    if (i < EBMAX / 2) ebuf32[i] = 0x4E204E20u;   // two u16 = NN, NN (zero row)
}

// ---------------- scan stage 1: padded-degree block scan + block sums ------
__global__ __launch_bounds__(256) void k_scan1(const int* __restrict__ degi,
                                               int* __restrict__ rowptr,
                                               int* __restrict__ bsum) {
    int t = threadIdx.x;
    int i = blockIdx.x * 256 + t;
    int v = (i < NN) ? ((degi[i] + 7) & ~7) : 0;   // padded degree (8)
    int lane = t & 63, wid = t >> 6;
    int x = v;
#pragma unroll
    for (int off = 1; off < 64; off <<= 1) {
        int y = __shfl_up(x, off);
        if (lane >= off) x += y;
    }
    __shared__ int ws[4];
    if (lane == 63) ws[wid] = x;
    __syncthreads();
    int woff = 0;
    for (int w = 0; w < wid; ++w) woff += ws[w];
    if (i < NN) rowptr[i] = woff + x - v;
    if (t == 255) bsum[blockIdx.x] = woff + x;
}

// ---------------- scan 2+3 fused: fixup + cursor + dinv + u0 (+zero row NN)
__global__ void k_scan3(const int* __restrict__ degi, const int* __restrict__ bsum,
                        int* __restrict__ rowptr, int* __restrict__ cursor,
                        float* __restrict__ dinv,
                        const float* __restrict__ x, u16* __restrict__ u0) {
    __shared__ int pref[NB];
    if (threadIdx.x < NB) pref[threadIdx.x] = bsum[threadIdx.x];
    __syncthreads();
    if (threadIdx.x == 0) {
        int run = 0;
        for (int k = 0; k < NB; ++k) { int t = pref[k]; pref[k] = run; run += t; }
    }
    __syncthreads();
    int i = blockIdx.x * 256 + threadIdx.x;
    if (i < NN) {
        int dg = degi[i];
        int rp = rowptr[i] + pref[i >> 8];
        rowptr[i] = rp;
        cursor[i] = rp;
        dinv[i] = rsqrtf((float)(1 + dg));
        if (i == NN - 1) rowptr[NN] = rp + ((dg + 7) & ~7);
    }
    if (i < NN * FIN / 4) {
        int node = i >> 4;
        float d = rsqrtf((float)(1 + degi[node]));
        float4 v = *(const float4*)&x[(size_t)i * 4];
        u32 lo = (u32)f2bf(v.x * d) | ((u32)f2bf(v.y * d) << 16);
        u32 hi = (u32)f2bf(v.z * d) | ((u32)f2bf(v.w * d) << 16);
        *(uint2*)&u0[(size_t)i * 4] = make_uint2(lo, hi);
    }
    if (blockIdx.x == 0 && threadIdx.x < FIN) u0[(size_t)NN * FIN + threadIdx.x] = 0;  // dummy row
}

// ---------------- fill CSR buckets (u16 payload) ----------------
__global__ void k_fill(const int* __restrict__ row, const int* __restrict__ col,
                       int* __restrict__ cursor, u16* __restrict__ ebuf) {
    int e = blockIdx.x * 256 + threadIdx.x;
    if (e < NE) {
        int c = col[e];
        int pos = atomicAdd(&cursor[c], 1);
        ebuf[pos] = (u16)row[e];
    }
}

// ---------------- LDS-tiled transpose+cast of all 5 W ----------------
__global__ __launch_bounds__(256) void k_trans(const float* __restrict__ W0, const float* __restrict__ W1,
                                               const float* __restrict__ W2, const float* __restrict__ W3,
                                               const float* __restrict__ W4,
                                               u16* __restrict__ T0, u16* __restrict__ T1,
                                               u16* __restrict__ T2, u16* __restrict__ T3,
                                               u16* __restrict__ T4) {
    int l = blockIdx.z;
    const float* W = (l == 0) ? W0 : (l == 1) ? W1 : (l == 2) ? W2 : (l == 3) ? W3 : W4;
    u16* T = (l == 0) ? T0 : (l == 1) ? T1 : (l == 2) ? T2 : (l == 3) ? T3 : T4;
    int K = (l == 0) ? FIN : HD;
    int k0 = blockIdx.x * 32;
    if (k0 >= K) return;
    int n0 = blockIdx.y * 32;
    __shared__ float tile[32][33];
    int tx = threadIdx.x & 31, ty = threadIdx.x >> 5;
#pragma unroll
    for (int r = 0; r < 32; r += 8)
        tile[ty + r][tx] = W[(size_t)(k0 + ty + r) * HD + n0 + tx];
    __syncthreads();
#pragma unroll
    for (int r = 0; r < 32; r += 8)
        T[(size_t)(n0 + ty + r) * K + k0 + tx] = f2bf(tile[tx][ty + r]);
}

// ============ FUSED gather(aggregate) + MFMA matmul, 16-row tile/block =====
// Best-measured configuration (r9, 322 us): pad-8 CSR; 256-wide gather is
// FULL-ROW no-reduce (lane owns 4 feats of the 256-feat row, one uint2 load
// per neighbor row, chunk ids via one broadcast uint4, zero cross-lane
// reduction); 64-wide layer-1 keeps the grp/seg path. MFMA: Bsm cooperative
// staging. Aggregation is cache random-line service-rate bound (~42 us/layer
// at ~3.2M 64-B lines); occupancy/MLP/locality levers all measured neutral.
__global__ __launch_bounds__(512, 8) void k_fused(const u16* __restrict__ U,
                                                  const int* __restrict__ rowptr,
                                                  const u16* __restrict__ ebuf,
                                                  const float* __restrict__ dinv,
                                                  const u16* __restrict__ Wt,
                                                  const float* __restrict__ bias,
                                                  u16* __restrict__ O,
                                                  int K, int scaleOut) {
    __shared__ u16 Asm[16][264];     // 16 rows x (K<=256 + 8 pad) bf16
    __shared__ u16 Bsm[256][40];
    __shared__ float bs[HD];
    const int m0 = blockIdx.x * 16;  // 1250 * 16 == 20000, exact
    const int t = threadIdx.x;
    const int wave = t >> 6;         // 0..7
    const int lane = t & 63;
    if (t < HD) bs[t] = bias[t];
    if (blockIdx.x == 0 && t < HD) O[(size_t)NN * HD + t] = 0;   // dummy row

    // ---------------- gather phase ----------------
    if (K == HD) {
        // full-row: task = node, 16 tasks, 2/wave; lane owns feats [lane*4, lane*4+4)
        const int f0 = lane * 4;
        for (int task = wave; task < 16; task += 8) {
            const int n = m0 + task;
            const int s = rowptr[n], e = rowptr[n + 1];
            float acc[4];
            {   // self-loop (every lane owns its 4 feats)
                uint2 sv = *(const uint2*)&U[(size_t)n * HD + f0];
                acc[0] = bf2f((u16)(sv.x & 0xffff)); acc[1] = bf2f((u16)(sv.x >> 16));
                acc[2] = bf2f((u16)(sv.y & 0xffff)); acc[3] = bf2f((u16)(sv.y >> 16));
            }
            for (int j0 = s; j0 < e; j0 += 8) {
                uint4 iv = *(const uint4*)&ebuf[j0];   // 8 ids, broadcast (1 line)
                // batch 1: rows 0..3 in flight
                uint2 v0 = *(const uint2*)&U[(size_t)(iv.x & 0xffff) * HD + f0];
                uint2 v1 = *(const uint2*)&U[(size_t)(iv.x >> 16)    * HD + f0];
                uint2 v2 = *(const uint2*)&U[(size_t)(iv.y & 0xffff) * HD + f0];
                uint2 v3 = *(const uint2*)&U[(size_t)(iv.y >> 16)    * HD + f0];
                accum4(acc, v0); accum4(acc, v1); accum4(acc, v2); accum4(acc, v3);
                // batch 2: rows 4..7
                uint2 v4 = *(const uint2*)&U[(size_t)(iv.z & 0xffff) * HD + f0];
                uint2 v5 = *(const uint2*)&U[(size_t)(iv.z >> 16)    * HD + f0];
                uint2 v6 = *(const uint2*)&U[(size_t)(iv.w & 0xffff) * HD + f0];
                uint2 v7 = *(const uint2*)&U[(size_t)(iv.w >> 16)    * HD + f0];
                accum4(acc, v4); accum4(acc, v5); accum4(acc, v6); accum4(acc, v7);
            }
            float d = dinv[n];
            uint2 o;
            o.x = (u32)f2bf(acc[0] * d) | ((u32)f2bf(acc[1] * d) << 16);
            o.y = (u32)f2bf(acc[2] * d) | ((u32)f2bf(acc[3] * d) << 16);
            *(uint2*)&Asm[task][f0] = o;
        }
    } else {
        // 64-wide rows (layer 1): task = node, 16 tasks, 2/wave
        const int grp = lane >> 3;       // 0..7
        const int seg = lane & 7;        // 16-B feature segment
        for (int task = wave; task < 16; task += 8) {
            const int n = m0 + task;
            const int s = rowptr[n], e = rowptr[n + 1];
            float acc[8];
            if (grp == 0) {
                uint4 v = *(const uint4*)&U[(size_t)n * FIN + seg * 8];
                acc[0] = bf2f((u16)(v.x & 0xffff)); acc[1] = bf2f((u16)(v.x >> 16));
                acc[2] = bf2f((u16)(v.y & 0xffff)); acc[3] = bf2f((u16)(v.y >> 16));
                acc[4] = bf2f((u16)(v.z & 0xffff)); acc[5] = bf2f((u16)(v.z >> 16));
                acc[6] = bf2f((u16)(v.w & 0xffff)); acc[7] = bf2f((u16)(v.w >> 16));
            } else {
#pragma unroll
                for (int k = 0; k < 8; ++k) acc[k] = 0.f;
            }
            for (int j = s; j < e; j += 8) {
                int r0 = (int)ebuf[j + grp];                      // pads -> row NN
                uint4 v0 = *(const uint4*)&U[(size_t)r0 * FIN + seg * 8];
                accum8(acc, v0);
            }
#pragma unroll
            for (int off = 8; off < 64; off <<= 1)
#pragma unroll
                for (int k = 0; k < 8; ++k) acc[k] += __shfl_xor(acc[k], off);
            if (grp == 0) {
                float d = dinv[n];
                uint4 o;
                o.x = (u32)f2bf(acc[0] * d) | ((u32)f2bf(acc[1] * d) << 16);
                o.y = (u32)f2bf(acc[2] * d) | ((u32)f2bf(acc[3] * d) << 16);
                o.z = (u32)f2bf(acc[4] * d) | ((u32)f2bf(acc[5] * d) << 16);
                o.w = (u32)f2bf(acc[6] * d) | ((u32)f2bf(acc[7] * d) << 16);
                *(uint4*)&Asm[task][seg * 8] = o;
            }
        }
    }
    __syncthreads();

    // ---------------- MFMA phase (Bsm cooperative staging) ----------------
    const int quad = lane >> 4;
    const int l16 = lane & 15;
    const int n0 = wave * 32;        // wave owns N columns [n0, n0+32)
    f32x4 acc[2];
#pragma unroll
    for (int j = 0; j < 2; ++j) acc[j] = (f32x4){0.f, 0.f, 0.f, 0.f};

    for (int k0 = 0; k0 < K; k0 += 32) {
        {   // stage Wt[:, k0:k0+32] (16 KB) with all 512 threads
            int r = t >> 1, h16 = (t & 1) * 16;
#pragma unroll
            for (int j = 0; j < 2; ++j) {
                float4 v = *(const float4*)&Wt[(size_t)r * K + k0 + h16 + j * 8];
                *(float4*)&Bsm[r][h16 + j * 8] = v;
            }
        }
        __syncthreads();
        short8 a = *(const short8*)&Asm[l16][k0 + quad * 8];
        short8 b[2];
#pragma unroll
        for (int j = 0; j < 2; ++j) b[j] = *(const short8*)&Bsm[n0 + j * 16 + l16][quad * 8];
#pragma unroll
        for (int j = 0; j < 2; ++j)
            acc[j] = __builtin_amdgcn_mfma_f32_16x16x32_bf16(a, b[j], acc[j], 0, 0, 0);
        __syncthreads();
    }
#pragma unroll
    for (int r = 0; r < 4; ++r) {
        int m = m0 + quad * 4 + r;
        float d = scaleOut ? dinv[m] : 1.0f;
#pragma unroll
        for (int j = 0; j < 2; ++j) {
            int n = n0 + j * 16 + l16;
            float val = fmaxf(acc[j][r] + bs[n], 0.f) * d;
            O[(size_t)m * HD + n] = f2bf(val);
        }
    }
}

// ---------------- fused pool + head (512 thr: 2 node-stripes) ----------------
__global__ __launch_bounds__(512) void k_poolout(const u16* __restrict__ h,
                                                 const int* __restrict__ gstart,
                                                 const float* __restrict__ Wout,
                                                 const float* __restrict__ bout,
                                                 float* __restrict__ out) {
    int g = blockIdx.x;
    int t = threadIdx.x;
    int f = t & (HD - 1);
    int half = t >> 8;               // 0 or 1
    __shared__ float pp[2][HD];
    __shared__ float pooled[HD];
    __shared__ float part[NC][16];
    __shared__ int s_se[2];
    if (t == 0) {
        int st = gstart[g];
        int en = NN;
        for (int gg = g + 1; gg < NG; ++gg) en = min(en, gstart[gg]);
        s_se[0] = st; s_se[1] = en;
    }
    __syncthreads();
    int st = s_se[0], en = s_se[1];
    float a0 = 0.f, a1 = 0.f, a2 = 0.f, a3 = 0.f;
    int n = st + half;
    for (; n + 6 < en; n += 8) {
        a0 += bf2f(h[(size_t)n * HD + f]);
        a1 += bf2f(h[(size_t)(n + 2) * HD + f]);
        a2 += bf2f(h[(size_t)(n + 4) * HD + f]);
        a3 += bf2f(h[(size_t)(n + 6) * HD + f]);
    }
    for (; n < en; n += 2) a0 += bf2f(h[(size_t)n * HD + f]);
    pp[half][f] = a0 + a1 + a2 + a3;
    __syncthreads();
    if (t < HD) {
        float inv = 1.0f / (float)max(en - st, 1);
        pooled[t] = (pp[0][t] + pp[1][t]) * inv;
    }
    __syncthreads();
    if (t < NC * 16) {
        int c = t >> 4, l16 = t & 15;
        float s = 0.f;
        for (int ff = l16; ff < HD; ff += 16)
            s = fmaf(pooled[ff], Wout[(size_t)ff * NC + c], s);
        part[c][l16] = s;
    }
    __syncthreads();
    if (t < NC) {
        float s = 0.f;
#pragma unroll
        for (int k = 0; k < 16; ++k) s += part[t][k];
        out[(size_t)g * NC + t] = s + bout[t];
    }
}

extern "C" void kernel_launch(void* const* d_in, const int* in_sizes, int n_in,
                              void* d_out, int out_size, void* d_ws, size_t ws_size,
                              hipStream_t stream) {
    const float* x     = (const float*)d_in[0];
    const int*   ei    = (const int*)d_in[1];
    const int*   batch = (const int*)d_in[2];
    const float* Wl[5] = {(const float*)d_in[3], (const float*)d_in[5], (const float*)d_in[7],
                          (const float*)d_in[9], (const float*)d_in[11]};
    const float* bl[5] = {(const float*)d_in[4], (const float*)d_in[6], (const float*)d_in[8],
                          (const float*)d_in[10], (const float*)d_in[12]};
    const float* Wout = (const float*)d_in[13];
    const float* bout = (const float*)d_in[14];
    float* out = (float*)d_out;

    const int* row = ei;
    const int* col = ei + NE;

    char* p = (char*)d_ws;
    auto take = [&](size_t bytes) { char* q = p; p += (bytes + 255) & ~(size_t)255; return q; };
    float* dinv   = (float*)take(NN * 4);
    int*   degi   = (int*)take(NN * 4);
    int*   rowptr = (int*)take((NN + 1) * 4);
    int*   cursor = (int*)take(NN * 4);
    int*   bsum   = (int*)take(NB * 4);
    u16*   ebuf   = (u16*)take(EBMAX * 2);
    int*   gstart = (int*)take(NG * 4);
    u16*   Wt[5];
    for (int l = 0; l < 5; ++l) Wt[l] = (u16*)take((size_t)HD * HD * 2);
    u16*   B1     = (u16*)take((size_t)(NN + 1) * HD * 2);   // +1 dummy zero row
    u16*   B2     = (u16*)take((size_t)(NN + 1) * HD * 2);

    hipMemsetAsync(degi, 0, NN * 4, stream);
    hipMemsetAsync(gstart, 0x7F, NG * 4, stream);   // sentinel > NN
    k_degpad<<<(NE + 255) / 256, 256, 0, stream>>>(col, degi, batch, gstart, (u32*)ebuf);
    k_scan1<<<NB, 256, 0, stream>>>(degi, rowptr, bsum);
    k_scan3<<<(NN * FIN / 4 + 255) / 256, 256, 0, stream>>>(degi, bsum, rowptr, cursor, dinv, x, B1);
    k_fill<<<(NE + 255) / 256, 256, 0, stream>>>(row, col, cursor, ebuf);
    dim3 tGrid(8, 8, 5);
    k_trans<<<tGrid, 256, 0, stream>>>(Wl[0], Wl[1], Wl[2], Wl[3], Wl[4],
                                       Wt[0], Wt[1], Wt[2], Wt[3], Wt[4]);

    // 5 fused layers, ping-pong B1 <-> B2 (U != O, no read/write hazard)
    const int fGrid = NN / 16;   // 1250, exact
    k_fused<<<fGrid, 512, 0, stream>>>(B1, rowptr, ebuf, dinv, Wt[0], bl[0], B2, FIN, 1);
    k_fused<<<fGrid, 512, 0, stream>>>(B2, rowptr, ebuf, dinv, Wt[1], bl[1], B1, HD, 1);
    k_fused<<<fGrid, 512, 0, stream>>>(B1, rowptr, ebuf, dinv, Wt[2], bl[2], B2, HD, 1);
    k_fused<<<fGrid, 512, 0, stream>>>(B2, rowptr, ebuf, dinv, Wt[3], bl[3], B1, HD, 1);
    k_fused<<<fGrid, 512, 0, stream>>>(B1, rowptr, ebuf, dinv, Wt[4], bl[4], B2, HD, 0);

    k_poolout<<<NG, 512, 0, stream>>>(B2, gstart, Wout, bout, out);
}